// Round 1
// baseline (167.434 us; speedup 1.0000x reference)
//
#include <hip/hip_runtime.h>
#include <hip/hip_bf16.h>

#define INF_SENT 1.0e6f
#define ALPHA 1.0f
#define INV_BETA 0.5f

// ---------------------------------------------------------------------------
// K1: exact vertical 1-D distance (two sequential min-scans), store g^2.
// One thread per (b, j) column. grid = B, block = W.
// ---------------------------------------------------------------------------
__global__ void edt_vertical_kernel(const int* __restrict__ mask,
                                    float* __restrict__ g2,
                                    int H, int W) {
    const int b = blockIdx.x;
    const int j = threadIdx.x;
    const long base = (long)b * H * W + j;

    // forward scan: c = min(c+1, col_init)
    float c = INF_SENT;
    for (int i = 0; i < H; ++i) {
        float ci = mask[base + (long)i * W] ? 0.0f : INF_SENT;
        c = fminf(c + 1.0f, ci);
        g2[base + (long)i * W] = c;   // stash forward pass
    }
    // backward scan, combine, square
    c = INF_SENT;
    for (int i = H - 1; i >= 0; --i) {
        float ci = mask[base + (long)i * W] ? 0.0f : INF_SENT;
        c = fminf(c + 1.0f, ci);
        float g = fminf(g2[base + (long)i * W], c);
        g2[base + (long)i * W] = g * g;
    }
}

// ---------------------------------------------------------------------------
// K2: per-row exact horizontal pass + CE + weight + block reduction.
// One block per row (b,i), one thread per column j. grid = B*H, block = W.
// ---------------------------------------------------------------------------
__global__ void loss_row_kernel(const float* __restrict__ pred,
                                const int* __restrict__ mask,
                                const float* __restrict__ g2,
                                float* __restrict__ block_sums,
                                int H, int W) {
    const int row = blockIdx.x;        // b*H + i
    const int b = row / H;
    const int i = row - b * H;
    const int j = threadIdx.x;

    __shared__ float s_g2[256];
    __shared__ float s_part[4];

    const long rbase = (long)row * W;
    s_g2[j] = g2[rbase + j];
    __syncthreads();

    // exact 2D: d2 = min_k g2[k] + (j-k)^2  (uniform k => LDS broadcast)
    float best = 1e30f;
    #pragma unroll 8
    for (int k = 0; k < 256; ++k) {
        float dk = (float)(j - k);
        best = fminf(best, s_g2[k] + dk * dk);
    }

    float w = expf(-sqrtf(best) * INV_BETA);   // underflows to 0 when no bright pts

    // 2-class CE from logits
    const long pbase = (((long)b * 2) * H + i) * W + j;
    float p0 = pred[pbase];
    float p1 = pred[pbase + (long)H * W];
    int   t  = mask[rbase + j];
    float m  = fmaxf(p0, p1);
    float lse = m + logf(expf(p0 - m) + expf(p1 - m));
    float ce  = lse - (t ? p1 : p0);

    float v = ce * (1.0f + ALPHA * w);

    // wave-64 shuffle reduce, then cross-wave via LDS
    for (int off = 32; off > 0; off >>= 1)
        v += __shfl_down(v, off, 64);
    const int lane = j & 63;
    const int wid  = j >> 6;
    if (lane == 0) s_part[wid] = v;
    __syncthreads();
    if (j == 0) {
        float s = s_part[0] + s_part[1] + s_part[2] + s_part[3];
        block_sums[row] = s;
    }
}

// ---------------------------------------------------------------------------
// K3: deterministic final reduction of B*H partials -> mean.
// ---------------------------------------------------------------------------
__global__ void final_reduce_kernel(const float* __restrict__ block_sums,
                                    float* __restrict__ out,
                                    int n, float scale) {
    __shared__ float s_part[4];
    float v = 0.0f;
    for (int idx = threadIdx.x; idx < n; idx += 256)
        v += block_sums[idx];
    for (int off = 32; off > 0; off >>= 1)
        v += __shfl_down(v, off, 64);
    const int lane = threadIdx.x & 63;
    const int wid  = threadIdx.x >> 6;
    if (lane == 0) s_part[wid] = v;
    __syncthreads();
    if (threadIdx.x == 0)
        out[0] = (s_part[0] + s_part[1] + s_part[2] + s_part[3]) * scale;
}

extern "C" void kernel_launch(void* const* d_in, const int* in_sizes, int n_in,
                              void* d_out, int out_size, void* d_ws, size_t ws_size,
                              hipStream_t stream) {
    const int B = 16, H = 256, W = 256;
    const float* pred = (const float*)d_in[0];          // [B,2,H,W] f32
    const int*   mask = (const int*)d_in[1];            // [B,H,W] i32
    // d_in[2] (background_mask) unused by the reference loss.
    float* out = (float*)d_out;

    float* g2         = (float*)d_ws;                               // B*H*W floats (4 MB)
    float* block_sums = (float*)((char*)d_ws + (size_t)B * H * W * sizeof(float)); // B*H floats

    edt_vertical_kernel<<<B, W, 0, stream>>>(mask, g2, H, W);
    loss_row_kernel<<<B * H, W, 0, stream>>>(pred, mask, g2, block_sums, H, W);
    final_reduce_kernel<<<1, 256, 0, stream>>>(block_sums, out, B * H,
                                               1.0f / (float)(B * H * W));
}

// Round 2
// 105.934 us; speedup vs baseline: 1.5805x; 1.5805x over previous
//
#include <hip/hip_runtime.h>
#include <hip/hip_bf16.h>

#define INF_SENT 1.0e6f
#define ALPHA 1.0f
#define INV_BETA 0.5f

#define B_ 16
#define H_ 256
#define W_ 256
#define SEG 16
#define NSEG 16   // H_/SEG

// ---------------------------------------------------------------------------
// K1a: per-segment summaries for the vertical prefix/suffix min.
//   sumA[b,s,j] = min_{i in seg} (init[i] - i)   (init = mask?0:1e6)
//   sumB[b,s,j] = min_{i in seg} (init[i] + i)
// grid = B*NSEG blocks, block = W threads (coalesced over j).
// ---------------------------------------------------------------------------
__global__ void edt_seg_summary(const int* __restrict__ mask,
                                float* __restrict__ sumA,
                                float* __restrict__ sumB) {
    const int bs = blockIdx.x;
    const int b  = bs >> 4;
    const int s  = bs & (NSEG - 1);
    const int j  = threadIdx.x;
    const int i0 = s * SEG;
    const long base = ((long)b * H_ + i0) * W_ + j;

    float mA = 1e30f, mB = 1e30f;
    #pragma unroll
    for (int r = 0; r < SEG; ++r) {
        float init = mask[base + (long)r * W_] ? 0.0f : INF_SENT;
        float fi = (float)(i0 + r);
        mA = fminf(mA, init - fi);
        mB = fminf(mB, init + fi);
    }
    sumA[(long)bs * W_ + j] = mA;
    sumB[(long)bs * W_ + j] = mB;
}

// ---------------------------------------------------------------------------
// K1b: apply carries + in-register 16-row scan, write g^2.
//   F_i = i + min(carryP, running prefix of init-i)   (exact fwd distance)
//   Bw_i = min(carryS, running suffix of init+i) - i  (exact bwd distance)
//   g2 = min(F,Bw)^2  -- bitwise identical to reference fmin chains.
// ---------------------------------------------------------------------------
__global__ void edt_seg_apply(const int* __restrict__ mask,
                              const float* __restrict__ sumA,
                              const float* __restrict__ sumB,
                              float* __restrict__ g2) {
    const int bs = blockIdx.x;
    const int b  = bs >> 4;
    const int s  = bs & (NSEG - 1);
    const int j  = threadIdx.x;
    const int i0 = s * SEG;
    const long base = ((long)b * H_ + i0) * W_ + j;

    float carryP = 1e30f;
    for (int sp = 0; sp < s; ++sp)
        carryP = fminf(carryP, sumA[((long)b * NSEG + sp) * W_ + j]);
    float carryS = 1e30f;
    for (int sp = s + 1; sp < NSEG; ++sp)
        carryS = fminf(carryS, sumB[((long)b * NSEG + sp) * W_ + j]);

    float init[SEG];
    #pragma unroll
    for (int r = 0; r < SEG; ++r)
        init[r] = mask[base + (long)r * W_] ? 0.0f : INF_SENT;

    float F[SEG];
    float P = carryP;
    #pragma unroll
    for (int r = 0; r < SEG; ++r) {
        float fi = (float)(i0 + r);
        P = fminf(P, init[r] - fi);
        F[r] = fi + P;
    }
    float S = carryS;
    #pragma unroll
    for (int r = SEG - 1; r >= 0; --r) {
        float fi = (float)(i0 + r);
        S = fminf(S, init[r] + fi);
        float g = fminf(F[r], S - fi);
        g2[base + (long)r * W_] = g * g;
    }
}

// ---------------------------------------------------------------------------
// Fallback serial EDT (used only if ws too small; matches round-0 kernel).
// ---------------------------------------------------------------------------
__global__ void edt_vertical_kernel(const int* __restrict__ mask,
                                    float* __restrict__ g2,
                                    int H, int W) {
    const int b = blockIdx.x;
    const int j = threadIdx.x;
    const long base = (long)b * H * W + j;
    float c = INF_SENT;
    for (int i = 0; i < H; ++i) {
        float ci = mask[base + (long)i * W] ? 0.0f : INF_SENT;
        c = fminf(c + 1.0f, ci);
        g2[base + (long)i * W] = c;
    }
    c = INF_SENT;
    for (int i = H - 1; i >= 0; --i) {
        float ci = mask[base + (long)i * W] ? 0.0f : INF_SENT;
        c = fminf(c + 1.0f, ci);
        float g = fminf(g2[base + (long)i * W], c);
        g2[base + (long)i * W] = g * g;
    }
}

// ---------------------------------------------------------------------------
// K2: per-row exact horizontal pass + CE + weight + block reduction.
// ---------------------------------------------------------------------------
__global__ void loss_row_kernel(const float* __restrict__ pred,
                                const int* __restrict__ mask,
                                const float* __restrict__ g2,
                                float* __restrict__ block_sums,
                                int H, int W) {
    const int row = blockIdx.x;        // b*H + i
    const int b = row / H;
    const int i = row - b * H;
    const int j = threadIdx.x;

    __shared__ float s_g2[256];
    __shared__ float s_part[4];

    const long rbase = (long)row * W;
    s_g2[j] = g2[rbase + j];
    __syncthreads();

    float best = 1e30f;
    #pragma unroll 8
    for (int k = 0; k < 256; ++k) {
        float dk = (float)(j - k);
        best = fminf(best, s_g2[k] + dk * dk);
    }

    float w = expf(-sqrtf(best) * INV_BETA);

    const long pbase = (((long)b * 2) * H + i) * W + j;
    float p0 = pred[pbase];
    float p1 = pred[pbase + (long)H * W];
    int   t  = mask[rbase + j];
    float m  = fmaxf(p0, p1);
    float lse = m + logf(expf(p0 - m) + expf(p1 - m));
    float ce  = lse - (t ? p1 : p0);

    float v = ce * (1.0f + ALPHA * w);

    for (int off = 32; off > 0; off >>= 1)
        v += __shfl_down(v, off, 64);
    const int lane = j & 63;
    const int wid  = j >> 6;
    if (lane == 0) s_part[wid] = v;
    __syncthreads();
    if (j == 0)
        block_sums[row] = s_part[0] + s_part[1] + s_part[2] + s_part[3];
}

__global__ void final_reduce_kernel(const float* __restrict__ block_sums,
                                    float* __restrict__ out,
                                    int n, float scale) {
    __shared__ float s_part[4];
    float v = 0.0f;
    for (int idx = threadIdx.x; idx < n; idx += 256)
        v += block_sums[idx];
    for (int off = 32; off > 0; off >>= 1)
        v += __shfl_down(v, off, 64);
    const int lane = threadIdx.x & 63;
    const int wid  = threadIdx.x >> 6;
    if (lane == 0) s_part[wid] = v;
    __syncthreads();
    if (threadIdx.x == 0)
        out[0] = (s_part[0] + s_part[1] + s_part[2] + s_part[3]) * scale;
}

extern "C" void kernel_launch(void* const* d_in, const int* in_sizes, int n_in,
                              void* d_out, int out_size, void* d_ws, size_t ws_size,
                              hipStream_t stream) {
    const int B = B_, H = H_, W = W_;
    const float* pred = (const float*)d_in[0];          // [B,2,H,W] f32
    const int*   mask = (const int*)d_in[1];            // [B,H,W] i32
    float* out = (float*)d_out;

    const size_t n_g2   = (size_t)B * H * W;            // 1M floats
    const size_t n_rows = (size_t)B * H;                // 4096
    const size_t n_sum  = (size_t)B * NSEG * W;         // 64K floats

    float* g2         = (float*)d_ws;
    float* block_sums = g2 + n_g2;
    float* sumA       = block_sums + n_rows;
    float* sumB       = sumA + n_sum;
    const size_t need = (n_g2 + n_rows + 2 * n_sum) * sizeof(float);

    if (ws_size >= need) {
        edt_seg_summary<<<B * NSEG, W, 0, stream>>>(mask, sumA, sumB);
        edt_seg_apply<<<B * NSEG, W, 0, stream>>>(mask, sumA, sumB, g2);
    } else {
        edt_vertical_kernel<<<B, W, 0, stream>>>(mask, g2, H, W);
    }
    loss_row_kernel<<<B * H, W, 0, stream>>>(pred, mask, g2, block_sums, H, W);
    final_reduce_kernel<<<1, 256, 0, stream>>>(block_sums, out, B * H,
                                               1.0f / (float)(B * H * W));
}

// Round 3
// 25.009 us; speedup vs baseline: 6.6948x; 4.2358x over previous
//
#include <hip/hip_runtime.h>
#include <hip/hip_bf16.h>

#define INF_SENT 1.0e6f
#define ALPHA 1.0f
#define INV_BETA 0.5f

#define B_ 16
#define H_ 256
#define W_ 256
#define SEG 16
#define NSEG 16   // H_/SEG

// ---------------------------------------------------------------------------
// K1a: per-segment summaries for the vertical prefix/suffix min.
//   sumA[b,s,j] = min_{i in seg} (init[i] - i)   (init = mask?0:1e6)
//   sumB[b,s,j] = min_{i in seg} (init[i] + i)
// ---------------------------------------------------------------------------
__global__ void edt_seg_summary(const int* __restrict__ mask,
                                float* __restrict__ sumA,
                                float* __restrict__ sumB) {
    const int bs = blockIdx.x;
    const int b  = bs >> 4;
    const int s  = bs & (NSEG - 1);
    const int j  = threadIdx.x;
    const int i0 = s * SEG;
    const long base = ((long)b * H_ + i0) * W_ + j;

    float mA = 1e30f, mB = 1e30f;
    #pragma unroll
    for (int r = 0; r < SEG; ++r) {
        float init = mask[base + (long)r * W_] ? 0.0f : INF_SENT;
        float fi = (float)(i0 + r);
        mA = fminf(mA, init - fi);
        mB = fminf(mB, init + fi);
    }
    sumA[(long)bs * W_ + j] = mA;
    sumB[(long)bs * W_ + j] = mB;
}

// ---------------------------------------------------------------------------
// K1b: apply carries + in-register 16-row scan, write g^2 (exact vertical EDT).
// ---------------------------------------------------------------------------
__global__ void edt_seg_apply(const int* __restrict__ mask,
                              const float* __restrict__ sumA,
                              const float* __restrict__ sumB,
                              float* __restrict__ g2) {
    const int bs = blockIdx.x;
    const int b  = bs >> 4;
    const int s  = bs & (NSEG - 1);
    const int j  = threadIdx.x;
    const int i0 = s * SEG;
    const long base = ((long)b * H_ + i0) * W_ + j;

    float carryP = 1e30f;
    for (int sp = 0; sp < s; ++sp)
        carryP = fminf(carryP, sumA[((long)b * NSEG + sp) * W_ + j]);
    float carryS = 1e30f;
    for (int sp = s + 1; sp < NSEG; ++sp)
        carryS = fminf(carryS, sumB[((long)b * NSEG + sp) * W_ + j]);

    float init[SEG];
    #pragma unroll
    for (int r = 0; r < SEG; ++r)
        init[r] = mask[base + (long)r * W_] ? 0.0f : INF_SENT;

    float F[SEG];
    float P = carryP;
    #pragma unroll
    for (int r = 0; r < SEG; ++r) {
        float fi = (float)(i0 + r);
        P = fminf(P, init[r] - fi);
        F[r] = fi + P;
    }
    float S = carryS;
    #pragma unroll
    for (int r = SEG - 1; r >= 0; --r) {
        float fi = (float)(i0 + r);
        S = fminf(S, init[r] + fi);
        float g = fminf(F[r], S - fi);
        g2[base + (long)r * W_] = g * g;
    }
}

// ---------------------------------------------------------------------------
// Fallback serial EDT (used only if ws too small).
// ---------------------------------------------------------------------------
__global__ void edt_vertical_kernel(const int* __restrict__ mask,
                                    float* __restrict__ g2,
                                    int H, int W) {
    const int b = blockIdx.x;
    const int j = threadIdx.x;
    const long base = (long)b * H * W + j;
    float c = INF_SENT;
    for (int i = 0; i < H; ++i) {
        float ci = mask[base + (long)i * W] ? 0.0f : INF_SENT;
        c = fminf(c + 1.0f, ci);
        g2[base + (long)i * W] = c;
    }
    c = INF_SENT;
    for (int i = H - 1; i >= 0; --i) {
        float ci = mask[base + (long)i * W] ? 0.0f : INF_SENT;
        c = fminf(c + 1.0f, ci);
        float g = fminf(g2[base + (long)i * W], c);
        g2[base + (long)i * W] = g * g;
    }
}

// ---------------------------------------------------------------------------
// K2: per-row horizontal pass (adaptive outward expansion, exact) + CE +
// weight + block reduction. One block per row (b,i).
//
// Exactness of early exit: every skipped term fl(g2[k]+r2) >= r2 >= best,
// since a+b >= max(a,b) for non-negative floats and r2 is representable.
// ---------------------------------------------------------------------------
__global__ void loss_row_kernel(const float* __restrict__ pred,
                                const int* __restrict__ mask,
                                const float* __restrict__ g2,
                                float* __restrict__ block_sums,
                                int H, int W) {
    const int row = blockIdx.x;        // b*H + i
    const int b = row >> 8;
    const int i = row & 255;
    const int j = threadIdx.x;

    __shared__ float s_g2[256];
    __shared__ float s_part[4];

    const long rbase = (long)row * W;
    s_g2[j] = g2[rbase + j];
    __syncthreads();

    // adaptive exact 2D min: expand outward from k=j, stop when r^2 >= best
    float best = s_g2[j];
    for (int r = 1; r < W; ++r) {
        float r2 = (float)(r * r);
        if (r2 >= best) break;
        int kl = j - r, kr = j + r;
        if (kl >= 0) best = fminf(best, s_g2[kl] + r2);
        if (kr < W)  best = fminf(best, s_g2[kr] + r2);
    }

    float w = expf(-sqrtf(best) * INV_BETA);   // 0 when no bright points

    const long pbase = (((long)b * 2) * H + i) * W + j;
    float p0 = pred[pbase];
    float p1 = pred[pbase + (long)H * W];
    int   t  = mask[rbase + j];
    float m  = fmaxf(p0, p1);
    float lse = m + logf(expf(p0 - m) + expf(p1 - m));
    float ce  = lse - (t ? p1 : p0);

    float v = ce * (1.0f + ALPHA * w);

    for (int off = 32; off > 0; off >>= 1)
        v += __shfl_down(v, off, 64);
    const int lane = j & 63;
    const int wid  = j >> 6;
    if (lane == 0) s_part[wid] = v;
    __syncthreads();
    if (j == 0)
        block_sums[row] = s_part[0] + s_part[1] + s_part[2] + s_part[3];
}

__global__ void final_reduce_kernel(const float* __restrict__ block_sums,
                                    float* __restrict__ out,
                                    int n, float scale) {
    __shared__ float s_part[16];
    float v = 0.0f;
    for (int idx = threadIdx.x; idx < n; idx += 1024)
        v += block_sums[idx];
    for (int off = 32; off > 0; off >>= 1)
        v += __shfl_down(v, off, 64);
    const int lane = threadIdx.x & 63;
    const int wid  = threadIdx.x >> 6;
    if (lane == 0) s_part[wid] = v;
    __syncthreads();
    if (threadIdx.x == 0) {
        float s = 0.0f;
        #pragma unroll
        for (int k = 0; k < 16; ++k) s += s_part[k];
        out[0] = s * scale;
    }
}

extern "C" void kernel_launch(void* const* d_in, const int* in_sizes, int n_in,
                              void* d_out, int out_size, void* d_ws, size_t ws_size,
                              hipStream_t stream) {
    const int B = B_, H = H_, W = W_;
    const float* pred = (const float*)d_in[0];          // [B,2,H,W] f32
    const int*   mask = (const int*)d_in[1];            // [B,H,W] i32
    float* out = (float*)d_out;

    const size_t n_g2   = (size_t)B * H * W;            // 1M floats
    const size_t n_rows = (size_t)B * H;                // 4096
    const size_t n_sum  = (size_t)B * NSEG * W;         // 64K floats

    float* g2         = (float*)d_ws;
    float* block_sums = g2 + n_g2;
    float* sumA       = block_sums + n_rows;
    float* sumB       = sumA + n_sum;
    const size_t need = (n_g2 + n_rows + 2 * n_sum) * sizeof(float);

    if (ws_size >= need) {
        edt_seg_summary<<<B * NSEG, W, 0, stream>>>(mask, sumA, sumB);
        edt_seg_apply<<<B * NSEG, W, 0, stream>>>(mask, sumA, sumB, g2);
    } else {
        edt_vertical_kernel<<<B, W, 0, stream>>>(mask, g2, H, W);
    }
    loss_row_kernel<<<B * H, W, 0, stream>>>(pred, mask, g2, block_sums, H, W);
    final_reduce_kernel<<<1, 1024, 0, stream>>>(block_sums, out, B * H,
                                                1.0f / (float)(B * H * W));
}